// Round 12
// baseline (578.951 us; speedup 1.0000x reference)
//
#include <hip/hip_runtime.h>

// GAT as flash-attention, round 12: barrier-free, LDS-free phase 2.
//  - All phase2 loads are L2-resident (bitmask replaced the adj stream; per-
//    batch working set ~3.5 MB fits one XCD L2; b=bx&3 gives XCD affinity).
//    K/V MFMA fragments read DIRECTLY from global (indexing proven in R4),
//    software-pipelined 2-slot chunk prefetch -> no __syncthreads at all,
//    16 independent waves/CU. R4's failure (adj HBM in the in-order vmcnt
//    queue) no longer applies.
//  - mask+phase1 fused into one launch (phase1 blocks first, co-run).
//  - fixed-scale softmax (exp2), S^T MFMA formulation, 4-way j-split.

typedef __attribute__((ext_vector_type(4))) float f32x4;
typedef __attribute__((ext_vector_type(4))) _Float16 h16x4;
typedef __attribute__((ext_vector_type(8))) _Float16 h16x8;
typedef __attribute__((ext_vector_type(2))) __fp16 fp16x2;
typedef unsigned long long u64;

#define L2E 1.4426950408889634f

// ---------------- phase 0+1 fused: mask stream + h = x@W -------------------
// blocks 0..511: phase1 (LDS GEMM). blocks 512..16895: one adj row each,
// copy-shaped int4 reads (4 KB in flight per wave), ballot-packed bitmask.
// word[row][4k+c] bit l = adj[row][256k+4l+c] > 0.
__global__ __launch_bounds__(256) void gat_phase01(
    const float* __restrict__ x,        // [4][4096][128]
    const float* __restrict__ W,        // [128][64]
    const float* __restrict__ a,        // [192]
    const int* __restrict__ adj,        // [16384][4096]
    u64* __restrict__ mask,             // [16384][64]
    _Float16* __restrict__ h16,         // [4][4096][64]
    _Float16* __restrict__ hT16,        // [4][64][4096]
    _Float16* __restrict__ q16,         // [4][4096][64]  (pre-scaled by log2e)
    float* __restrict__ sS,             // [4][4096]      (pre-scaled by log2e)
    float* __restrict__ sN)             // [4][4096]      (pre-scaled by log2e)
{
  __shared__ float xs[32 * 132];
  __shared__ float ws[128 * 64];
  const int tid = threadIdx.x;
  const int w = tid >> 6, lane = tid & 63;

  if (blockIdx.x >= 512) {
    // ---- mask path ----
    const size_t row = blockIdx.x - 512;
    const int* ap = adj + row * 4096 + 4 * lane;
    u64* mp = mask + row * 64;
    int4 v0 = *(const int4*)(ap + (w + 0) * 256);
    int4 v1 = *(const int4*)(ap + (w + 4) * 256);
    int4 v2 = *(const int4*)(ap + (w + 8) * 256);
    int4 v3 = *(const int4*)(ap + (w + 12) * 256);
#define BALLOT4(v, k)                                            \
    {                                                            \
      u64 b0 = __ballot(v.x > 0); u64 b1 = __ballot(v.y > 0);    \
      u64 b2 = __ballot(v.z > 0); u64 b3 = __ballot(v.w > 0);    \
      if (lane == 0) {                                           \
        mp[4 * (k) + 0] = b0; mp[4 * (k) + 1] = b1;              \
        mp[4 * (k) + 2] = b2; mp[4 * (k) + 3] = b3;              \
      }                                                          \
    }
    BALLOT4(v0, w + 0); BALLOT4(v1, w + 4);
    BALLOT4(v2, w + 8); BALLOT4(v3, w + 12);
#undef BALLOT4
    return;
  }

  // ---- phase1 path (unchanged internals) ----
  const int bx  = blockIdx.x;
  const int b   = bx >> 7;
  const int n0  = (bx & 127) << 5;
  const float* xb = x + ((size_t)b * 4096 + n0) * 128;

#pragma unroll
  for (int p = 0; p < 4; ++p) {
    int idx = tid + p * 256;
    int row = idx >> 5, c4 = idx & 31;
    float4 v = ((const float4*)(xb + row * 128))[c4];
    *(float4*)&xs[row * 132 + c4 * 4] = v;
  }
#pragma unroll
  for (int p = 0; p < 8; ++p) {
    int idx = tid + p * 256;
    ((float4*)ws)[idx] = ((const float4*)W)[idx];
  }
  __syncthreads();

  const int tx = tid & 15;   // f = 4*tx + fi
  const int ty = tid >> 4;   // n = n0 + 2*ty + ri
  f32x4 acc0 = (f32x4){0.f, 0.f, 0.f, 0.f};
  f32x4 acc1 = (f32x4){0.f, 0.f, 0.f, 0.f};

#pragma unroll 8
  for (int k = 0; k < 128; k += 4) {
    f32x4 x0 = *(const f32x4*)&xs[(2 * ty) * 132 + k];
    f32x4 x1 = *(const f32x4*)&xs[(2 * ty + 1) * 132 + k];
    f32x4 w0 = *(const f32x4*)&ws[(k + 0) * 64 + 4 * tx];
    f32x4 w1 = *(const f32x4*)&ws[(k + 1) * 64 + 4 * tx];
    f32x4 w2 = *(const f32x4*)&ws[(k + 2) * 64 + 4 * tx];
    f32x4 w3 = *(const f32x4*)&ws[(k + 3) * 64 + 4 * tx];
    acc0 += x0.x * w0 + x0.y * w1 + x0.z * w2 + x0.w * w3;
    acc1 += x1.x * w0 + x1.y * w1 + x1.z * w2 + x1.w * w3;
  }
  float acc[2][4] = {{acc0.x, acc0.y, acc0.z, acc0.w},
                     {acc1.x, acc1.y, acc1.z, acc1.w}};

  float a1r[4], a2r[4], a3r[4];
#pragma unroll
  for (int f = 0; f < 4; ++f) {
    a1r[f] = a[4 * tx + f] * L2E;
    a2r[f] = a[64 + 4 * tx + f] * L2E;
    a3r[f] = a[128 + 4 * tx + f] * L2E;
  }
  const size_t bN = (size_t)b * 4096;
#pragma unroll
  for (int r = 0; r < 2; ++r) {
    float p1 = 0.f, p2 = 0.f;
#pragma unroll
    for (int f = 0; f < 4; ++f) { p1 += acc[r][f] * a1r[f]; p2 += acc[r][f] * a2r[f]; }
#pragma unroll
    for (int m = 1; m < 16; m <<= 1) {
      p1 += __shfl_xor(p1, m, 64);
      p2 += __shfl_xor(p2, m, 64);
    }
    if (tx == 0) {
      int n = n0 + 2 * ty + r;
      sS[bN + n] = p1;
      sN[bN + n] = p2;
    }
  }
#pragma unroll
  for (int r = 0; r < 2; ++r) {
    int n = n0 + 2 * ty + r;
    h16x4 hv, qv;
#pragma unroll
    for (int f = 0; f < 4; ++f) {
      hv[f] = (_Float16)acc[r][f];
      qv[f] = (_Float16)(acc[r][f] * a3r[f]);
    }
    *(h16x4*)&h16[(bN + n) * 64 + 4 * tx] = hv;
    *(h16x4*)&q16[(bN + n) * 64 + 4 * tx] = qv;
  }
  __syncthreads();                       // xs reads done; reuse as hT staging
  _Float16* hTs = (_Float16*)xs;         // [64][40] halves
#pragma unroll
  for (int f = 0; f < 4; ++f)
#pragma unroll
    for (int r = 0; r < 2; ++r)
      hTs[(4 * tx + f) * 40 + 2 * ty + r] = (_Float16)acc[r][f];
  __syncthreads();
  {
    int f = tid >> 2, part = tid & 3;
    uint4 v = *(uint4*)&hTs[f * 40 + 8 * part];
    *(uint4*)&hT16[((size_t)b * 64 + f) * 4096 + n0 + 8 * part] = v;
  }
}

// ---------------- phase 2: masked softmax-attention partials ----------------
// 1024 blocks (b(4), split(4), itile(64)) x 256 thr = 4 INDEPENDENT waves of
// 16 i-rows. No LDS, no barriers. j-quarter = 1024 = 64 chunks of 16; K/V/sn
// fragments loaded direct from global (all L2-hot), 2-slot pipeline (chunk
// u+2 issued after computing chunk u). Mask: 8 B per 64 j per lane.
// MFMA layouts: 16x16x32 A[m=lane&15][k=qd*8+j], B[k=qd*8+j][n=lane&15],
//               16x16x16 A[m][k=qd*4+r], B[k][n], C/D row=4*qd+reg, col=lane&15.
__global__ __launch_bounds__(256, 4) void gat_phase2(
    const _Float16* __restrict__ h16,
    const _Float16* __restrict__ hT16,
    const _Float16* __restrict__ q16,
    const float* __restrict__ sS,
    const float* __restrict__ sN,
    const u64* __restrict__ mask,       // [16384][64]
    float* __restrict__ Opart,          // [4][16384][64]
    float* __restrict__ lpart)          // [4][16384]
{
  const int tid = threadIdx.x;
  const int w = tid >> 6, lane = tid & 63;
  const int qd = lane >> 4, c = lane & 15;
  const int bx = blockIdx.x;
  const int b = bx & 3;
  const int split = (bx >> 2) & 3;
  const int it = bx >> 4;
  const int i0 = it * 64 + w * 16;
  const int jq0 = split * 1024;
  const size_t bN = (size_t)b * 4096;

  // Q fragment (B-op of S^T): lane holds Q[i=i0+c][f-slice]
  const _Float16* qrow = q16 + (bN + i0 + c) * 64;
  h16x8 Qf0 = *(const h16x8*)(qrow + qd * 8);
  h16x8 Qf1 = *(const h16x8*)(qrow + 32 + qd * 8);
  const float ss = sS[bN + i0 + c];

  const u64* mrow = mask + (bN + i0 + c) * 64 + (jq0 >> 8) * 4;

  // direct-global fragment bases (indexing proven in R4)
  const _Float16* kbase = h16 + (bN + jq0 + c) * 64 + qd * 8;      // +j*64
  const _Float16* vbase = hT16 + ((size_t)b * 64 + c) * 4096 + jq0 + 4 * qd;
  const float* snb = sN + bN + jq0 + 4 * qd;

  f32x4 O[4];
#pragma unroll
  for (int ft = 0; ft < 4; ++ft) O[ft] = (f32x4){0.f, 0.f, 0.f, 0.f};
  float lsum = 0.f;

#define LOADC(K0, K1, V, SN, u)                                   \
  {                                                               \
    const int j0_ = (u) * 16;                                     \
    K0 = *(const h16x8*)(kbase + j0_ * 64);                       \
    K1 = *(const h16x8*)(kbase + j0_ * 64 + 32);                  \
    V[0] = *(const h16x4*)(vbase + 0 * 65536 + j0_);              \
    V[1] = *(const h16x4*)(vbase + 1 * 65536 + j0_);              \
    V[2] = *(const h16x4*)(vbase + 2 * 65536 + j0_);              \
    V[3] = *(const h16x4*)(vbase + 3 * 65536 + j0_);              \
    SN = *(const f32x4*)(snb + j0_);                              \
  }

#define COMPUTE(K0, K1, V, SN, CT)                                \
  {                                                               \
    f32x4 Sv = (f32x4){0.f, 0.f, 0.f, 0.f};                       \
    Sv = __builtin_amdgcn_mfma_f32_16x16x32_f16(K0, Qf0, Sv, 0, 0, 0); \
    Sv = __builtin_amdgcn_mfma_f32_16x16x32_f16(K1, Qf1, Sv, 0, 0, 0); \
    f32x4 ev = Sv + SN + ss;                                      \
    f32x4 tv = __builtin_elementwise_max(ev, ev * 0.2f);          \
    float p0 = __builtin_amdgcn_exp2f(tv.x);                      \
    float p1 = __builtin_amdgcn_exp2f(tv.y);                      \
    float p2 = __builtin_amdgcn_exp2f(tv.z);                      \
    float p3 = __builtin_amdgcn_exp2f(tv.w);                      \
    p0 = ((T0 >> (4 * (CT))) & 1u) ? p0 : 0.f;                    \
    p1 = ((T1 >> (4 * (CT))) & 1u) ? p1 : 0.f;                    \
    p2 = ((T2s >> (4 * (CT))) & 1u) ? p2 : 0.f;                   \
    p3 = ((T3 >> (4 * (CT))) & 1u) ? p3 : 0.f;                    \
    lsum += (p0 + p1) + (p2 + p3);                                \
    fp16x2 plo = __builtin_amdgcn_cvt_pkrtz(p0, p1);              \
    fp16x2 phi = __builtin_amdgcn_cvt_pkrtz(p2, p3);              \
    h16x4 Pf = (h16x4){(_Float16)plo.x, (_Float16)plo.y,          \
                       (_Float16)phi.x, (_Float16)phi.y};         \
    O[0] = __builtin_amdgcn_mfma_f32_16x16x16f16(V[0], Pf, O[0], 0, 0, 0); \
    O[1] = __builtin_amdgcn_mfma_f32_16x16x16f16(V[1], Pf, O[1], 0, 0, 0); \
    O[2] = __builtin_amdgcn_mfma_f32_16x16x16f16(V[2], Pf, O[2], 0, 0, 0); \
    O[3] = __builtin_amdgcn_mfma_f32_16x16x16f16(V[3], Pf, O[3], 0, 0, 0); \
  }

  // pipeline: two chunk slots; prologue loads chunks 0 and 1
  h16x8 Ka0, Ka1, Kb0, Kb1;
  h16x4 Va[4], Vb[4];
  f32x4 sna, snc;
  LOADC(Ka0, Ka1, Va, sna, 0);
  LOADC(Kb0, Kb1, Vb, snc, 1);

  u64 W0 = mrow[0], W1 = mrow[1], W2 = mrow[2], W3 = mrow[3];

  for (int g = 0; g < 4; ++g) {
    u64 N0 = W0, N1 = W1, N2 = W2, N3 = W3;
    if (g < 3) {                                  // prefetch next mask group
      const u64* mg = mrow + 4 * (g + 1);
      N0 = mg[0]; N1 = mg[1]; N2 = mg[2]; N3 = mg[3];
    }
#pragma unroll
    for (int tt = 0; tt < 4; ++tt) {
      const int t = 4 * g + tt;
      const unsigned T0  = ((unsigned)(W0 >> (16 * tt))) >> qd;
      const unsigned T1  = ((unsigned)(W1 >> (16 * tt))) >> qd;
      const unsigned T2s = ((unsigned)(W2 >> (16 * tt))) >> qd;
      const unsigned T3  = ((unsigned)(W3 >> (16 * tt))) >> qd;

      COMPUTE(Ka0, Ka1, Va, sna, 0);              // chunk 4t
      LOADC(Ka0, Ka1, Va, sna, 4 * t + 2);        // always <= 62
      COMPUTE(Kb0, Kb1, Vb, snc, 1);              // chunk 4t+1
      LOADC(Kb0, Kb1, Vb, snc, 4 * t + 3);        // always <= 63
      COMPUTE(Ka0, Ka1, Va, sna, 2);              // chunk 4t+2
      if (t < 15) LOADC(Ka0, Ka1, Va, sna, 4 * t + 4);
      COMPUTE(Kb0, Kb1, Vb, snc, 3);              // chunk 4t+3
      if (t < 15) LOADC(Kb0, Kb1, Vb, snc, 4 * t + 5);
    }
    W0 = N0; W1 = N1; W2 = N2; W3 = N3;
  }
#undef LOADC
#undef COMPUTE

  // l: sum over qd groups (full j-quarter per row i=i0+c)
  lsum += __shfl_xor(lsum, 16, 64);
  lsum += __shfl_xor(lsum, 32, 64);

  float* orow = Opart + ((size_t)split * 16384 + bN + i0 + c) * 64;
#pragma unroll
  for (int ft = 0; ft < 4; ++ft)
    *(f32x4*)(orow + 16 * ft + 4 * qd) = O[ft];
  if (lane < 16) lpart[split * 16384 + bN + i0 + c] = lsum;
}

// ---------------- phase 3: combine splits + normalize + ELU ----------------
__global__ __launch_bounds__(256) void gat_combine(
    const float* __restrict__ Opart, const float* __restrict__ lpart,
    float* __restrict__ out)
{
  const int tid = threadIdx.x;
  const size_t row = (size_t)blockIdx.x * 16 + (tid >> 4);
  const int f4 = (tid & 15) * 4;
  const size_t R = 16384;
  float l = lpart[row] + lpart[R + row] + lpart[2 * R + row] + lpart[3 * R + row];
  f32x4 o = *(const f32x4*)&Opart[row * 64 + f4];
  o += *(const f32x4*)&Opart[(R + row) * 64 + f4];
  o += *(const f32x4*)&Opart[(2 * R + row) * 64 + f4];
  o += *(const f32x4*)&Opart[(3 * R + row) * 64 + f4];
  float inv = 1.0f / l;
  float4 res;
  float v;
  v = o.x * inv; res.x = v > 0.f ? v : __expf(v) - 1.f;
  v = o.y * inv; res.y = v > 0.f ? v : __expf(v) - 1.f;
  v = o.z * inv; res.z = v > 0.f ? v : __expf(v) - 1.f;
  v = o.w * inv; res.w = v > 0.f ? v : __expf(v) - 1.f;
  *(float4*)&out[row * 64 + f4] = res;
}

extern "C" void kernel_launch(void* const* d_in, const int* in_sizes, int n_in,
                              void* d_out, int out_size, void* d_ws, size_t ws_size,
                              hipStream_t stream) {
  const float* x  = (const float*)d_in[0];
  const int* adj  = (const int*)d_in[1];
  const float* W  = (const float*)d_in[2];
  const float* a  = (const float*)d_in[3];
  float* out = (float*)d_out;

  char* ws = (char*)d_ws;
  _Float16* h16  = (_Float16*)(ws);                      // 2 MB
  _Float16* hT16 = (_Float16*)(ws + (2u << 20));         // 2 MB
  _Float16* q16  = (_Float16*)(ws + (4u << 20));         // 2 MB
  float* sS = (float*)(ws + (6u << 20));                 // 64 KB
  float* sN = (float*)(ws + (6u << 20) + (64u << 10));   // 64 KB
  float* Opart = (float*)(ws + (6u << 20) + (128u << 10));               // 16.8 MB
  float* lpart = (float*)(ws + (6u << 20) + (128u << 10) + (17u << 20)); // 256 KB
  u64* mask =
      (u64*)(ws + (6u << 20) + (128u << 10) + (18u << 20)); // 8.4 MB

  gat_phase01<<<16896, 256, 0, stream>>>(x, W, a, adj, mask,
                                         h16, hT16, q16, sS, sN);
  gat_phase2<<<1024, 256, 0, stream>>>(h16, hT16, q16, sS, sN, mask, Opart, lpart);
  gat_combine<<<1024, 256, 0, stream>>>(Opart, lpart, out);
}